// Round 6
// baseline (1191.607 us; speedup 1.0000x reference)
//
#include <hip/hip_runtime.h>
#include <hip/hip_bf16.h>
#include <math.h>

#define BB 2
#define TT 1024
#define DD 1024
#define NH 16
#define KVHN 4
#define NL 4
#define II 2730
#define IIP 2816          // padded intermediate (multiple of 128)
#define NTOK (BB * TT)
#define QKVD 1536         // fused q(1024)+kv(512) width
#define KSTR 72           // padded LDS row stride (bf16) for attention tiles

typedef __hip_bfloat16 bf16;
typedef __attribute__((ext_vector_type(8))) short bf16x8;
typedef __attribute__((ext_vector_type(4))) float f32x4;

#define GLOAD16(gp, lp)                                                        \
    __builtin_amdgcn_global_load_lds(                                          \
        (const __attribute__((address_space(1))) unsigned int*)(gp),           \
        (__attribute__((address_space(3))) unsigned int*)(lp), 16, 0, 0)

__device__ inline float b2f(unsigned short u) {
    union { unsigned int i; float f; } v;
    v.i = (unsigned int)u << 16;
    return v.f;
}
__device__ inline unsigned short f2b(float f) {
    __hip_bfloat16 b = __float2bfloat16(f);
    return *(unsigned short*)&b;
}

// ---------------- rope sin/cos table ----------------
__global__ void rope_table_k(float* __restrict__ st, float* __restrict__ ct) {
    int i = blockIdx.x * 256 + threadIdx.x;
    if (i >= TT * 64) return;
    int t = i >> 6, d = i & 63;
    float freq = powf(10000.0f, (float)(d & 31) / 32.0f);
    float ang = (float)t / freq;
    st[i] = sinf(ang);
    ct[i] = cosf(ang);
}

// ---------------- embedding gather (fp32 residual) ----------------
__global__ __launch_bounds__(256) void embed_k(const int* __restrict__ idx,
                                               const float* __restrict__ wte,
                                               float* __restrict__ x) {
    int row = blockIdx.x;
    int tok = idx[row];
    const float4* src = (const float4*)(wte + (size_t)tok * DD);
    float4* dst = (float4*)(x + (size_t)row * DD);
    dst[threadIdx.x] = src[threadIdx.x];
}

// ---------------- rmsnorm: fp32 in -> bf16 out ----------------
__global__ __launch_bounds__(256) void rmsnorm_k(const float* __restrict__ x,
                                                 const float* __restrict__ w,
                                                 bf16* __restrict__ o) {
    int row = blockIdx.x;
    float4 v = ((const float4*)(x + (size_t)row * DD))[threadIdx.x];
    float s = v.x * v.x + v.y * v.y + v.z * v.z + v.w * v.w;
#pragma unroll
    for (int off = 32; off > 0; off >>= 1) s += __shfl_down(s, off);
    __shared__ float red[4];
    if ((threadIdx.x & 63) == 0) red[threadIdx.x >> 6] = s;
    __syncthreads();
    float tot = red[0] + red[1] + red[2] + red[3];
    float r = rsqrtf(tot * (1.0f / DD) + 1e-6f);
    float4 wv = ((const float4*)w)[threadIdx.x];
    size_t base = (size_t)row * DD + threadIdx.x * 4;
    ushort4 ov;
    ov.x = f2b(v.x * r * wv.x);
    ov.y = f2b(v.y * r * wv.y);
    ov.z = f2b(v.z * r * wv.z);
    ov.w = f2b(v.w * r * wv.w);
    *(ushort4*)(o + base) = ov;
}

// ---------------- pack q/k with rope (fp32 qkv -> bf16), q pre-scaled ------
__global__ void pack_qk_k(const float* __restrict__ qkv,
                          const float* __restrict__ st, const float* __restrict__ ct,
                          bf16* __restrict__ qp, bf16* __restrict__ kp) {
    int i = blockIdx.x * 256 + threadIdx.x;
    if (i >= NTOK * 20 * 32) return;
    int row = i / 640;
    int rem = i - row * 640;
    int slot = rem >> 5;
    int d = rem & 31;
    int b = row >> 10;
    int t = row & (TT - 1);
    int off = (slot < 16) ? slot * 64 : 1024 + (slot - 16) * 64;
    const float* p = qkv + (size_t)row * QKVD + off;
    float x0 = p[d], x1 = p[d + 32];
    float c = ct[t * 64 + d], s = st[t * 64 + d];
    float o0 = x0 * c - x1 * s;
    float o1 = x1 * c + x0 * s;
    if (slot < 16) {
        o0 *= 0.125f; o1 *= 0.125f;  // 1/sqrt(64) folded into q
        bf16* q = qp + (((size_t)(b * NH + slot) * TT + t) * 64);
        q[d] = __float2bfloat16(o0);
        q[d + 32] = __float2bfloat16(o1);
    } else {
        bf16* k = kp + (((size_t)(b * KVHN + (slot - 16)) * TT + t) * 64);
        k[d] = __float2bfloat16(o0);
        k[d + 32] = __float2bfloat16(o1);
    }
}

// ---------------- pack v transposed: qkv v-cols -> vt[b][kvh][64][T] -------
__global__ __launch_bounds__(256) void pack_v_k(const float* __restrict__ qkv,
                                                bf16* __restrict__ vt) {
    int t0 = blockIdx.x * 64;
    int kvh = blockIdx.y;
    int b = blockIdx.z;
    __shared__ float Ls[64][65];
    int tid = threadIdx.x;
    for (int e = tid; e < 64 * 64; e += 256) {
        int tl = e >> 6, d = e & 63;
        Ls[tl][d] = qkv[((size_t)(b * TT + t0 + tl)) * QKVD + 1280 + kvh * 64 + d];
    }
    __syncthreads();
    for (int e = tid; e < 64 * 64; e += 256) {
        int d = e >> 6, tl = e & 63;
        vt[((size_t)(b * KVHN + kvh) * 64 + d) * TT + t0 + tl] = __float2bfloat16(Ls[tl][d]);
    }
}

// ---------------- MFMA flash attention (bf16, causal, GQA h%4) ------------
__global__ __launch_bounds__(256) void attn_mfma_k(const bf16* __restrict__ qp,
                                                   const bf16* __restrict__ kp,
                                                   const bf16* __restrict__ vt,
                                                   bf16* __restrict__ y) {
    int qt = blockIdx.x;
    int h = blockIdx.y;
    int b = blockIdx.z;
    int kvh = h & (KVHN - 1);

    __shared__ __align__(16) bf16 Ks[64][KSTR];
    __shared__ __align__(16) bf16 Vt[64][KSTR];       // [d][k]
    __shared__ __align__(16) bf16 Ps[4][16][KSTR];    // per-wave P[q][k]

    int tid = threadIdx.x;
    int lane = tid & 63;
    int w = tid >> 6;
    int qi = lane & 15;
    int g = lane >> 4;

    const bf16* qbase = qp + (((size_t)(b * NH + h) * TT + qt * 64 + w * 16 + qi) * 64);
    bf16x8 qf0 = *(const bf16x8*)(qbase + g * 8);
    bf16x8 qf1 = *(const bf16x8*)(qbase + 32 + g * 8);

    const bf16* kg = kp + ((size_t)(b * KVHN + kvh) * TT) * 64;
    const bf16* vg = vt + ((size_t)(b * KVHN + kvh) * 64) * TT;

    f32x4 oacc[4] = {};
    float m = -INFINITY, l = 0.0f;
    int qglob = qt * 64 + w * 16 + qi;

    for (int kt = 0; kt <= qt; ++kt) {
        __syncthreads();
        {
            int c0 = tid, c1 = tid + 256;
            *(bf16x8*)(&Ks[c0 >> 3][(c0 & 7) * 8]) =
                *(const bf16x8*)(kg + (size_t)(kt * 64 + (c0 >> 3)) * 64 + (c0 & 7) * 8);
            *(bf16x8*)(&Ks[c1 >> 3][(c1 & 7) * 8]) =
                *(const bf16x8*)(kg + (size_t)(kt * 64 + (c1 >> 3)) * 64 + (c1 & 7) * 8);
            *(bf16x8*)(&Vt[c0 >> 3][(c0 & 7) * 8]) =
                *(const bf16x8*)(vg + (size_t)(c0 >> 3) * TT + kt * 64 + (c0 & 7) * 8);
            *(bf16x8*)(&Vt[c1 >> 3][(c1 & 7) * 8]) =
                *(const bf16x8*)(vg + (size_t)(c1 >> 3) * TT + kt * 64 + (c1 & 7) * 8);
        }
        __syncthreads();

        f32x4 sacc[4] = {};
#pragma unroll
        for (int stt = 0; stt < 4; ++stt) {
            bf16x8 kf0 = *(const bf16x8*)(&Ks[stt * 16 + qi][g * 8]);
            bf16x8 kf1 = *(const bf16x8*)(&Ks[stt * 16 + qi][32 + g * 8]);
            sacc[stt] = __builtin_amdgcn_mfma_f32_16x16x32_bf16(kf0, qf0, sacc[stt], 0, 0, 0);
            sacc[stt] = __builtin_amdgcn_mfma_f32_16x16x32_bf16(kf1, qf1, sacc[stt], 0, 0, 0);
        }

        if (kt == qt) {
#pragma unroll
            for (int stt = 0; stt < 4; ++stt)
#pragma unroll
                for (int r = 0; r < 4; ++r) {
                    int kgl = kt * 64 + stt * 16 + g * 4 + r;
                    if (kgl > qglob) sacc[stt][r] = -INFINITY;
                }
        }

        float tmax = -INFINITY;
#pragma unroll
        for (int stt = 0; stt < 4; ++stt)
#pragma unroll
            for (int r = 0; r < 4; ++r) tmax = fmaxf(tmax, sacc[stt][r]);
        tmax = fmaxf(tmax, __shfl_xor(tmax, 16));
        tmax = fmaxf(tmax, __shfl_xor(tmax, 32));
        float mnew = fmaxf(m, tmax);
        float scale = __expf(m - mnew);
        float psum = 0.0f;
#pragma unroll
        for (int stt = 0; stt < 4; ++stt) {
            bf16 pb[4];
#pragma unroll
            for (int r = 0; r < 4; ++r) {
                float p = __expf(sacc[stt][r] - mnew);
                psum += p;
                pb[r] = __float2bfloat16(p);
            }
            *(uint2*)(&Ps[w][qi][stt * 16 + g * 4]) = *(uint2*)pb;
        }
        psum += __shfl_xor(psum, 16);
        psum += __shfl_xor(psum, 32);
        l = l * scale + psum;
        m = mnew;

        float sc0 = __shfl(scale, g * 4 + 0);
        float sc1 = __shfl(scale, g * 4 + 1);
        float sc2 = __shfl(scale, g * 4 + 2);
        float sc3 = __shfl(scale, g * 4 + 3);
#pragma unroll
        for (int dt = 0; dt < 4; ++dt) {
            oacc[dt][0] *= sc0; oacc[dt][1] *= sc1;
            oacc[dt][2] *= sc2; oacc[dt][3] *= sc3;
        }

#pragma unroll
        for (int kc = 0; kc < 2; ++kc) {
            bf16x8 pa = *(const bf16x8*)(&Ps[w][qi][kc * 32 + g * 8]);
#pragma unroll
            for (int dt = 0; dt < 4; ++dt) {
                bf16x8 vb = *(const bf16x8*)(&Vt[dt * 16 + qi][kc * 32 + g * 8]);
                oacc[dt] = __builtin_amdgcn_mfma_f32_16x16x32_bf16(pa, vb, oacc[dt], 0, 0, 0);
            }
        }
    }

    float linv = 1.0f / l;
    float li0 = __shfl(linv, g * 4 + 0);
    float li1 = __shfl(linv, g * 4 + 1);
    float li2 = __shfl(linv, g * 4 + 2);
    float li3 = __shfl(linv, g * 4 + 3);
#pragma unroll
    for (int dt = 0; dt < 4; ++dt) {
        int dcol = h * 64 + dt * 16 + qi;
        size_t r0 = (size_t)(b * TT + qt * 64 + w * 16 + g * 4) * DD + dcol;
        y[r0 + 0 * DD] = __float2bfloat16(oacc[dt][0] * li0);
        y[r0 + 1 * DD] = __float2bfloat16(oacc[dt][1] * li1);
        y[r0 + 2 * DD] = __float2bfloat16(oacc[dt][2] * li2);
        y[r0 + 3 * DD] = __float2bfloat16(oacc[dt][3] * li3);
    }
}

// ---------------- silu(g)*u from fused gu (bf16) -> gb (bf16), x4 vec ------
__global__ void silu_mul_k(const bf16* __restrict__ gu, bf16* __restrict__ gb) {
    int i4 = blockIdx.x * 256 + threadIdx.x;
    if (i4 >= NTOK * IIP / 4) return;
    int i = i4 * 4;
    int r = i / IIP, c = i - r * IIP;
    ushort4 gv = *(const ushort4*)(gu + (size_t)r * (2 * IIP) + c);
    ushort4 uv = *(const ushort4*)(gu + (size_t)r * (2 * IIP) + IIP + c);
    ushort4 o;
    {
        float g0 = b2f(gv.x); o.x = f2b(g0 / (1.0f + __expf(-g0)) * b2f(uv.x));
        float g1 = b2f(gv.y); o.y = f2b(g1 / (1.0f + __expf(-g1)) * b2f(uv.y));
        float g2 = b2f(gv.z); o.z = f2b(g2 / (1.0f + __expf(-g2)) * b2f(uv.z));
        float g3 = b2f(gv.w); o.w = f2b(g3 / (1.0f + __expf(-g3)) * b2f(uv.w));
    }
    *(ushort4*)(gb + i) = o;
}

// ---------------- bf16-A x fp32-W MFMA GEMM: C[N,M] = A @ Wvirt^T -----------
// W is a VIRTUAL [M][K] fp32 matrix: rows [0,split) from Wa (valid < rows_a),
// rows [split,M) from Wb (valid row-split < rows_b), cols >= Ksrc are zero.
// B is reg-staged fp32 -> cvt bf16 -> LDS; A via global_load_lds (bf16).
// 2-phase double-buffered K-loop (prefetch t+1 overlaps MFMA of t).
// MODE 0: C fp32; MODE 1: C fp32 += res; MODE 2: C bf16.
template <int MODE, int BM, int BN>
__global__ __launch_bounds__(256) void gemm_bt(const bf16* __restrict__ A,
                                               const float* __restrict__ Wa,
                                               const float* __restrict__ Wb,
                                               int split, int rows_a, int rows_b,
                                               int Ksrc, const float* res, void* Cv,
                                               int N, int M, int K) {
    constexpr int MF = BM / 32;
    constexpr int NF = BN / 32;
    __shared__ __align__(16) bf16 As[2 * BM * 32];
    __shared__ __align__(16) bf16 Bs[2 * BN * 32];

    int t = threadIdx.x;
    int nnt = N / BM;
    int nmt = M / BN;
    int nwg = nmt * nnt;
    int orig = blockIdx.x;
    int q8 = nwg >> 3;
    int wgid = (orig & 7) * q8 + (orig >> 3);   // XCD-chunked, bijective (nwg%8==0)
    int mt, nt;
    if constexpr (BN == 128) {                   // supertile 2m x nnt (nwg%32==0)
        int stile = wgid >> 5, rem = wgid & 31;
        mt = (stile << 1) + (rem & 1);
        nt = rem >> 1;
    } else {
        mt = wgid / nnt;
        nt = wgid - mt * nnt;
    }
    int m0 = mt * BN;
    int n0 = nt * BM;

    int lane = t & 63;
    int wave = t >> 6;
    int wr = (wave >> 1) * (BM / 2);
    int wc = (wave & 1) * (BN / 2);

    // A staging: chunk c -> row c>>2, k8 (c&3)*8; BM=128 has 2 chunks/thread
    const bf16* gA1 = A + (size_t)(n0 + (t >> 2)) * K + ((t & 3) * 8);
    const bf16* gA2 = (BM == 128) ? A + (size_t)(n0 + ((t + 256) >> 2)) * K + ((t & 3) * 8)
                                  : nullptr;

    // B staging: resolve virtual row -> source pointer once
    int bk1 = (t & 3) * 8;
    const float* wp1; bool wv1;
    {
        int vr = m0 + (t >> 2);
        if (vr < split) { wp1 = Wa + (size_t)vr * Ksrc; wv1 = vr < rows_a; }
        else            { wp1 = Wb + (size_t)(vr - split) * Ksrc; wv1 = (vr - split) < rows_b; }
    }
    const float* wp2 = nullptr; bool wv2 = false;
    if constexpr (BN == 128) {
        int vr = m0 + ((t + 256) >> 2);
        if (vr < split) { wp2 = Wa + (size_t)vr * Ksrc; wv2 = vr < rows_a; }
        else            { wp2 = Wb + (size_t)(vr - split) * Ksrc; wv2 = (vr - split) < rows_b; }
    }

    float4 p10, p11, p20, p21;

    auto issueA = [&](int buf, int k0) {
        GLOAD16(gA1 + k0, As + buf * (BM * 32) + t * 8);
        if constexpr (BM == 128)
            GLOAD16(gA2 + k0, As + buf * (BM * 32) + (t + 256) * 8);
    };
    auto load8 = [&](const float* wp, bool wv, int kb, float4& a, float4& b) {
        a = make_float4(0.f, 0.f, 0.f, 0.f); b = a;
        if (wv) {
            if (kb + 8 <= Ksrc) {
                a = *(const float4*)(wp + kb);
                b = *(const float4*)(wp + kb + 4);
            } else {
                float v[8];
#pragma unroll
                for (int i = 0; i < 8; i++) v[i] = (kb + i < Ksrc) ? wp[kb + i] : 0.0f;
                a = make_float4(v[0], v[1], v[2], v[3]);
                b = make_float4(v[4], v[5], v[6], v[7]);
            }
        }
    };
    auto loadB = [&](int k0) {
        load8(wp1, wv1, k0 + bk1, p10, p11);
        if constexpr (BN == 128) load8(wp2, wv2, k0 + bk1, p20, p21);
    };
    auto storeB = [&](int buf) {
        bf16x8 o;
        o[0] = (short)f2b(p10.x); o[1] = (short)f2b(p10.y);
        o[2] = (short)f2b(p10.z); o[3] = (short)f2b(p10.w);
        o[4] = (short)f2b(p11.x); o[5] = (short)f2b(p11.y);
        o[6] = (short)f2b(p11.z); o[7] = (short)f2b(p11.w);
        *(bf16x8*)(Bs + buf * (BN * 32) + t * 8) = o;
        if constexpr (BN == 128) {
            bf16x8 o2;
            o2[0] = (short)f2b(p20.x); o2[1] = (short)f2b(p20.y);
            o2[2] = (short)f2b(p20.z); o2[3] = (short)f2b(p20.w);
            o2[4] = (short)f2b(p21.x); o2[5] = (short)f2b(p21.y);
            o2[6] = (short)f2b(p21.z); o2[7] = (short)f2b(p21.w);
            *(bf16x8*)(Bs + buf * (BN * 32) + (t + 256) * 8) = o2;
        }
    };

    f32x4 acc[MF][NF] = {};
    int nsteps = K >> 5;

    // prologue: fill buffer 0
    issueA(0, 0);
    loadB(0);
    storeB(0);
    __syncthreads();   // drains gload_lds (vmcnt) + ds_write (lgkmcnt)

    for (int s = 0; s < nsteps; ++s) {
        int cur = s & 1;
        bool more = (s + 1 < nsteps);
        if (more) {            // prefetch t+1 while computing t
            issueA(cur ^ 1, (s + 1) << 5);
            loadB((s + 1) << 5);
        }

        const bf16* Ab = As + cur * (BM * 32);
        const bf16* Bb = Bs + cur * (BN * 32);
        bf16x8 af[MF], bfr[NF];
#pragma unroll
        for (int m = 0; m < MF; m++)
            af[m] = *(const bf16x8*)(Ab + (wr + m * 16 + (lane & 15)) * 32 + (lane >> 4) * 8);
#pragma unroll
        for (int n = 0; n < NF; n++)
            bfr[n] = *(const bf16x8*)(Bb + (wc + n * 16 + (lane & 15)) * 32 + (lane >> 4) * 8);
#pragma unroll
        for (int m = 0; m < MF; m++)
#pragma unroll
            for (int n = 0; n < NF; n++)
                acc[m][n] = __builtin_amdgcn_mfma_f32_16x16x32_bf16(af[m], bfr[n], acc[m][n], 0, 0, 0);

        if (more) storeB(cur ^ 1);   // cvt+LDS-write after MFMA (loads landed)
        __syncthreads();
    }

    float* Cf = (float*)Cv;
    bf16* Cb = (bf16*)Cv;
    int colb = m0 + wc + (lane & 15);
    int rowb = n0 + wr + (lane >> 4) * 4;
#pragma unroll
    for (int m = 0; m < MF; m++) {
#pragma unroll
        for (int n = 0; n < NF; n++) {
#pragma unroll
            for (int r = 0; r < 4; r++) {
                size_t off = (size_t)(rowb + m * 16 + r) * M + (colb + n * 16);
                float v = acc[m][n][r];
                if (MODE == 0) Cf[off] = v;
                if (MODE == 1) Cf[off] = v + res[off];
                if (MODE == 2) Cb[off] = __float2bfloat16(v);
            }
        }
    }
}

extern "C" void kernel_launch(void* const* d_in, const int* in_sizes, int n_in,
                              void* d_out, int out_size, void* d_ws, size_t ws_size,
                              hipStream_t stream) {
    const int* idx    = (const int*)d_in[0];
    const float* wte  = (const float*)d_in[1];
    const float* Wq   = (const float*)d_in[2];
    const float* Wkv  = (const float*)d_in[3];
    const float* Wo   = (const float*)d_in[4];
    const float* Wg   = (const float*)d_in[5];
    const float* Wu   = (const float*)d_in[6];
    const float* Wd   = (const float*)d_in[7];
    const float* rms1 = (const float*)d_in[8];
    const float* rms2 = (const float*)d_in[9];
    const float* rmsf = (const float*)d_in[10];
    float* out = (float*)d_out;

    char* ws = (char*)d_ws;
    size_t off = 0;
    float* x = (float*)(ws + off);  off += (size_t)NTOK * DD * 4;
    bf16* xn = (bf16*)(ws + off);   off += (size_t)NTOK * DD * 2;
    float* st = (float*)(ws + off); off += (size_t)TT * 64 * 4;
    float* ct = (float*)(ws + off); off += (size_t)TT * 64 * 4;
    float* qkv = (float*)(ws + off); off += (size_t)NTOK * QKVD * 4;
    bf16* yb = (bf16*)(ws + off);    off += (size_t)NTOK * DD * 2;
    bf16* gu = (bf16*)(ws + off);    off += (size_t)NTOK * 2 * IIP * 2;
    bf16* gb = (bf16*)(ws + off);    off += (size_t)NTOK * IIP * 2;
    bf16* qp = gu;                                    // aliases (gu dead here)
    bf16* kp = qp + (size_t)NTOK * DD;
    bf16* vt = kp + (size_t)BB * KVHN * TT * 64;

    rope_table_k<<<(TT * 64 + 255) / 256, 256, 0, stream>>>(st, ct);
    embed_k<<<NTOK, 256, 0, stream>>>(idx, wte, x);

    for (int l = 0; l < NL; ++l) {
        // --- attention block ---
        rmsnorm_k<<<NTOK, 256, 0, stream>>>(x, rms1 + (size_t)l * DD, xn);
        gemm_bt<0, 64, 64><<<(QKVD / 64) * (NTOK / 64), 256, 0, stream>>>(
            xn, Wq + (size_t)l * DD * DD, Wkv + (size_t)l * 512 * DD,
            1024, 1024, 512, DD, nullptr, qkv, NTOK, QKVD, DD);
        pack_qk_k<<<(NTOK * 20 * 32 + 255) / 256, 256, 0, stream>>>(qkv, st, ct, qp, kp);
        pack_v_k<<<dim3(TT / 64, KVHN, BB), 256, 0, stream>>>(qkv, vt);
        attn_mfma_k<<<dim3(TT / 64, NH, BB), 256, 0, stream>>>(qp, kp, vt, yb);
        gemm_bt<1, 64, 64><<<(DD / 64) * (NTOK / 64), 256, 0, stream>>>(
            yb, Wo + (size_t)l * DD * DD, nullptr,
            DD, DD, 0, DD, x, x, NTOK, DD, DD);
        // --- mlp block ---
        rmsnorm_k<<<NTOK, 256, 0, stream>>>(x, rms2 + (size_t)l * DD, xn);
        gemm_bt<2, 128, 128><<<(2 * IIP / 128) * (NTOK / 128), 256, 0, stream>>>(
            xn, Wg + (size_t)l * II * DD, Wu + (size_t)l * II * DD,
            IIP, II, II, DD, nullptr, gu, NTOK, 2 * IIP, DD);
        silu_mul_k<<<(NTOK * IIP / 4 + 255) / 256, 256, 0, stream>>>(gu, gb);
        gemm_bt<1, 64, 64><<<(DD / 64) * (NTOK / 64), 256, 0, stream>>>(
            gb, Wd + (size_t)l * DD * II, nullptr,
            DD, DD, 0, II, x, x, NTOK, DD, IIP);
    }

    // --- final norm + tied lm_head (fp32 wte read directly) ---
    rmsnorm_k<<<NTOK, 256, 0, stream>>>(x, rmsf, xn);
    gemm_bt<0, 128, 128><<<(32000 / 128) * (NTOK / 128), 256, 0, stream>>>(
        xn, wte, nullptr, 32000, 32000, 0, DD, nullptr, out, NTOK, 32000, DD);
}

// Round 7
// 1034.415 us; speedup vs baseline: 1.1520x; 1.1520x over previous
//
#include <hip/hip_runtime.h>
#include <hip/hip_bf16.h>
#include <math.h>

#define BB 2
#define TT 1024
#define DD 1024
#define NH 16
#define KVHN 4
#define NL 4
#define II 2730
#define IIP 2816          // padded intermediate (multiple of 128)
#define NTOK (BB * TT)
#define QKVD 1536         // fused q(1024)+kv(512) width
#define KSTR 72           // padded LDS row stride (bf16) for attention tiles

typedef __hip_bfloat16 bf16;
typedef __attribute__((ext_vector_type(8))) short bf16x8;
typedef __attribute__((ext_vector_type(4))) float f32x4;

#define GLOAD16(gp, lp)                                                        \
    __builtin_amdgcn_global_load_lds(                                          \
        (const __attribute__((address_space(1))) unsigned int*)(gp),           \
        (__attribute__((address_space(3))) unsigned int*)(lp), 16, 0, 0)

__device__ inline float b2f(unsigned short u) {
    union { unsigned int i; float f; } v;
    v.i = (unsigned int)u << 16;
    return v.f;
}
__device__ inline unsigned short f2b(float f) {
    __hip_bfloat16 b = __float2bfloat16(f);
    return *(unsigned short*)&b;
}

// ---------------- rope sin/cos table ----------------
__global__ void rope_table_k(float* __restrict__ st, float* __restrict__ ct) {
    int i = blockIdx.x * 256 + threadIdx.x;
    if (i >= TT * 64) return;
    int t = i >> 6, d = i & 63;
    float freq = powf(10000.0f, (float)(d & 31) / 32.0f);
    float ang = (float)t / freq;
    st[i] = sinf(ang);
    ct[i] = cosf(ang);
}

// ---------------- embedding gather (fp32 residual) ----------------
__global__ __launch_bounds__(256) void embed_k(const int* __restrict__ idx,
                                               const float* __restrict__ wte,
                                               float* __restrict__ x) {
    int row = blockIdx.x;
    int tok = idx[row];
    const float4* src = (const float4*)(wte + (size_t)tok * DD);
    float4* dst = (float4*)(x + (size_t)row * DD);
    dst[threadIdx.x] = src[threadIdx.x];
}

// ---------------- rmsnorm: fp32 in -> bf16 out ----------------
__global__ __launch_bounds__(256) void rmsnorm_k(const float* __restrict__ x,
                                                 const float* __restrict__ w,
                                                 bf16* __restrict__ o) {
    int row = blockIdx.x;
    float4 v = ((const float4*)(x + (size_t)row * DD))[threadIdx.x];
    float s = v.x * v.x + v.y * v.y + v.z * v.z + v.w * v.w;
#pragma unroll
    for (int off = 32; off > 0; off >>= 1) s += __shfl_down(s, off);
    __shared__ float red[4];
    if ((threadIdx.x & 63) == 0) red[threadIdx.x >> 6] = s;
    __syncthreads();
    float tot = red[0] + red[1] + red[2] + red[3];
    float r = rsqrtf(tot * (1.0f / DD) + 1e-6f);
    float4 wv = ((const float4*)w)[threadIdx.x];
    size_t base = (size_t)row * DD + threadIdx.x * 4;
    ushort4 ov;
    ov.x = f2b(v.x * r * wv.x);
    ov.y = f2b(v.y * r * wv.y);
    ov.z = f2b(v.z * r * wv.z);
    ov.w = f2b(v.w * r * wv.w);
    *(ushort4*)(o + base) = ov;
}

// ---------------- pack v transposed: vb[b][kvh][t][64] -> vt[b][kvh][64][T] -
__global__ __launch_bounds__(256) void pack_v_k(const bf16* __restrict__ vb,
                                                bf16* __restrict__ vt) {
    int t0 = blockIdx.x * 64;
    int kvh = blockIdx.y;
    int b = blockIdx.z;
    __shared__ unsigned short Ls[64][65];
    int tid = threadIdx.x;
    const unsigned short* vbs = (const unsigned short*)vb;
    unsigned short* vts = (unsigned short*)vt;
    for (int e = tid; e < 64 * 64; e += 256) {
        int tl = e >> 6, d = e & 63;
        Ls[tl][d] = vbs[((size_t)(b * KVHN + kvh) * TT + t0 + tl) * 64 + d];
    }
    __syncthreads();
    for (int e = tid; e < 64 * 64; e += 256) {
        int d = e >> 6, tl = e & 63;
        vts[((size_t)(b * KVHN + kvh) * 64 + d) * TT + t0 + tl] = Ls[tl][d];
    }
}

// ---------------- MFMA flash attention (bf16, causal, GQA h%4) ------------
__global__ __launch_bounds__(256) void attn_mfma_k(const bf16* __restrict__ qp,
                                                   const bf16* __restrict__ kp,
                                                   const bf16* __restrict__ vt,
                                                   bf16* __restrict__ y) {
    int qt = blockIdx.x;
    int h = blockIdx.y;
    int b = blockIdx.z;
    int kvh = h & (KVHN - 1);

    __shared__ __align__(16) bf16 Ks[64][KSTR];
    __shared__ __align__(16) bf16 Vt[64][KSTR];       // [d][k]
    __shared__ __align__(16) bf16 Ps[4][16][KSTR];    // per-wave P[q][k]

    int tid = threadIdx.x;
    int lane = tid & 63;
    int w = tid >> 6;
    int qi = lane & 15;
    int g = lane >> 4;

    const bf16* qbase = qp + (((size_t)(b * NH + h) * TT + qt * 64 + w * 16 + qi) * 64);
    bf16x8 qf0 = *(const bf16x8*)(qbase + g * 8);
    bf16x8 qf1 = *(const bf16x8*)(qbase + 32 + g * 8);

    const bf16* kg = kp + ((size_t)(b * KVHN + kvh) * TT) * 64;
    const bf16* vg = vt + ((size_t)(b * KVHN + kvh) * 64) * TT;

    f32x4 oacc[4] = {};
    float m = -INFINITY, l = 0.0f;
    int qglob = qt * 64 + w * 16 + qi;

    for (int kt = 0; kt <= qt; ++kt) {
        __syncthreads();
        {
            int c0 = tid, c1 = tid + 256;
            *(bf16x8*)(&Ks[c0 >> 3][(c0 & 7) * 8]) =
                *(const bf16x8*)(kg + (size_t)(kt * 64 + (c0 >> 3)) * 64 + (c0 & 7) * 8);
            *(bf16x8*)(&Ks[c1 >> 3][(c1 & 7) * 8]) =
                *(const bf16x8*)(kg + (size_t)(kt * 64 + (c1 >> 3)) * 64 + (c1 & 7) * 8);
            *(bf16x8*)(&Vt[c0 >> 3][(c0 & 7) * 8]) =
                *(const bf16x8*)(vg + (size_t)(c0 >> 3) * TT + kt * 64 + (c0 & 7) * 8);
            *(bf16x8*)(&Vt[c1 >> 3][(c1 & 7) * 8]) =
                *(const bf16x8*)(vg + (size_t)(c1 >> 3) * TT + kt * 64 + (c1 & 7) * 8);
        }
        __syncthreads();

        f32x4 sacc[4] = {};
#pragma unroll
        for (int stt = 0; stt < 4; ++stt) {
            bf16x8 kf0 = *(const bf16x8*)(&Ks[stt * 16 + qi][g * 8]);
            bf16x8 kf1 = *(const bf16x8*)(&Ks[stt * 16 + qi][32 + g * 8]);
            sacc[stt] = __builtin_amdgcn_mfma_f32_16x16x32_bf16(kf0, qf0, sacc[stt], 0, 0, 0);
            sacc[stt] = __builtin_amdgcn_mfma_f32_16x16x32_bf16(kf1, qf1, sacc[stt], 0, 0, 0);
        }

        if (kt == qt) {
#pragma unroll
            for (int stt = 0; stt < 4; ++stt)
#pragma unroll
                for (int r = 0; r < 4; ++r) {
                    int kgl = kt * 64 + stt * 16 + g * 4 + r;
                    if (kgl > qglob) sacc[stt][r] = -INFINITY;
                }
        }

        float tmax = -INFINITY;
#pragma unroll
        for (int stt = 0; stt < 4; ++stt)
#pragma unroll
            for (int r = 0; r < 4; ++r) tmax = fmaxf(tmax, sacc[stt][r]);
        tmax = fmaxf(tmax, __shfl_xor(tmax, 16));
        tmax = fmaxf(tmax, __shfl_xor(tmax, 32));
        float mnew = fmaxf(m, tmax);
        float scale = __expf(m - mnew);
        float psum = 0.0f;
#pragma unroll
        for (int stt = 0; stt < 4; ++stt) {
            bf16 pb[4];
#pragma unroll
            for (int r = 0; r < 4; ++r) {
                float p = __expf(sacc[stt][r] - mnew);
                psum += p;
                pb[r] = __float2bfloat16(p);
            }
            *(uint2*)(&Ps[w][qi][stt * 16 + g * 4]) = *(uint2*)pb;
        }
        psum += __shfl_xor(psum, 16);
        psum += __shfl_xor(psum, 32);
        l = l * scale + psum;
        m = mnew;

        float sc0 = __shfl(scale, g * 4 + 0);
        float sc1 = __shfl(scale, g * 4 + 1);
        float sc2 = __shfl(scale, g * 4 + 2);
        float sc3 = __shfl(scale, g * 4 + 3);
#pragma unroll
        for (int dt = 0; dt < 4; ++dt) {
            oacc[dt][0] *= sc0; oacc[dt][1] *= sc1;
            oacc[dt][2] *= sc2; oacc[dt][3] *= sc3;
        }

#pragma unroll
        for (int kc = 0; kc < 2; ++kc) {
            bf16x8 pa = *(const bf16x8*)(&Ps[w][qi][kc * 32 + g * 8]);
#pragma unroll
            for (int dt = 0; dt < 4; ++dt) {
                bf16x8 vb2 = *(const bf16x8*)(&Vt[dt * 16 + qi][kc * 32 + g * 8]);
                oacc[dt] = __builtin_amdgcn_mfma_f32_16x16x32_bf16(pa, vb2, oacc[dt], 0, 0, 0);
            }
        }
    }

    float linv = 1.0f / l;
    float li0 = __shfl(linv, g * 4 + 0);
    float li1 = __shfl(linv, g * 4 + 1);
    float li2 = __shfl(linv, g * 4 + 2);
    float li3 = __shfl(linv, g * 4 + 3);
#pragma unroll
    for (int dt = 0; dt < 4; ++dt) {
        int dcol = h * 64 + dt * 16 + qi;
        size_t r0 = (size_t)(b * TT + qt * 64 + w * 16 + g * 4) * DD + dcol;
        y[r0 + 0 * DD] = __float2bfloat16(oacc[dt][0] * li0);
        y[r0 + 1 * DD] = __float2bfloat16(oacc[dt][1] * li1);
        y[r0 + 2 * DD] = __float2bfloat16(oacc[dt][2] * li2);
        y[r0 + 3 * DD] = __float2bfloat16(oacc[dt][3] * li3);
    }
}

// ---------------- fp32 -> bf16 convert, padding + optional row interleave ---
__device__ inline void cvt_body(const float* __restrict__ src, bf16* __restrict__ dst,
                                int Msrc, int Ksrc, int Kdst, int total4,
                                int rmul, int radd, int start, int stride) {
    for (int i4 = start; i4 < total4; i4 += stride) {
        int i = i4 * 4;
        int r = i / Kdst, c = i - r * Kdst;
        ushort4 o;
        if (r < Msrc && c + 4 <= Ksrc && (Ksrc & 3) == 0) {
            float4 v = *(const float4*)(src + (size_t)r * Ksrc + c);
            o.x = f2b(v.x); o.y = f2b(v.y); o.z = f2b(v.z); o.w = f2b(v.w);
        } else {
            float v0 = (r < Msrc && c + 0 < Ksrc) ? src[(size_t)r * Ksrc + c + 0] : 0.0f;
            float v1 = (r < Msrc && c + 1 < Ksrc) ? src[(size_t)r * Ksrc + c + 1] : 0.0f;
            float v2 = (r < Msrc && c + 2 < Ksrc) ? src[(size_t)r * Ksrc + c + 2] : 0.0f;
            float v3 = (r < Msrc && c + 3 < Ksrc) ? src[(size_t)r * Ksrc + c + 3] : 0.0f;
            o.x = f2b(v0); o.y = f2b(v1); o.z = f2b(v2); o.w = f2b(v3);
        }
        *(ushort4*)(dst + ((size_t)(r * rmul + radd) * Kdst + c)) = o;
    }
}

struct CvtJobs {
    const float* src[6];
    bf16* dst[6];
    int Msrc[6], Ksrc[6], Kdst[6], n4[6], rmul[6], radd[6];
};
__global__ void cvt_fused_k(CvtJobs j) {
    int job = blockIdx.y;
    cvt_body(j.src[job], j.dst[job], j.Msrc[job], j.Ksrc[job], j.Kdst[job],
             j.n4[job], j.rmul[job], j.radd[job],
             blockIdx.x * 256 + threadIdx.x, gridDim.x * 256);
}

// ---------------- bf16 MFMA GEMM: C[N,M] = A[N,K] @ W[M,K]^T ----------------
// Single-buffer m97 core, 4 waves, 16x16x32 frags, XCD-chunk swizzle.
// WF32=1: B read from fp32 global, cvt in regs, ds_write (no weight cvt pass).
// MODE 0: C fp32 nontemporal.  MODE 1: C fp32 += res.
// MODE 3: silu-fused (W rows interleaved g/u) -> bf16 C [N, M/2].
// MODE 4: rope-fused qkv epilogue -> qp/kp/vb (BM=64, BN=128 required).
template <int MODE, int BM, int BN, int WF32>
__global__ __launch_bounds__(256) void gemm_bt(const bf16* __restrict__ A,
                                               const bf16* __restrict__ W16,
                                               const float* __restrict__ W32,
                                               const float* res, void* Cv,
                                               int N, int M, int K,
                                               const float* __restrict__ st,
                                               const float* __restrict__ ct,
                                               bf16* qp, bf16* kp, bf16* vb) {
    constexpr int MF = BM / 32;
    constexpr int NF = BN / 32;
    __shared__ __align__(16) bf16 As[BM * 32];
    __shared__ __align__(16) bf16 Bs[BN * 32];

    int t = threadIdx.x;
    int nnt = N / BM;
    int nmt = M / BN;
    int nwg = nmt * nnt;
    int orig = blockIdx.x;
    int q8 = nwg >> 3;
    int wgid = (orig & 7) * q8 + (orig >> 3);   // XCD-chunked, bijective (nwg%8==0)
    int mt, nt;
    if constexpr (BM == 128 && BN == 128) {
        // supertile 2m x 8n, m-pair fastest within n-half (A-half L2-resident).
        // requires nnt == 16, nmt even.
        int rem = wgid & 15;
        int sidx = wgid >> 4;
        int half = sidx / (nmt >> 1);
        int mpair = sidx - half * (nmt >> 1);
        mt = mpair * 2 + (rem & 1);
        nt = half * 8 + (rem >> 1);
    } else {
        mt = wgid / nnt;
        nt = wgid - mt * nnt;
    }
    int m0 = mt * BN;
    int n0 = nt * BM;

    int lane = t & 63;
    int wave = t >> 6;
    int wr = (wave >> 1) * (BM / 2);
    int wc = (wave & 1) * (BN / 2);
    int qi = lane & 15;
    int g4 = lane >> 4;

    const bf16* gA1 = A + (size_t)(n0 + (t >> 2)) * K + ((t & 3) * 8);
    const bf16* gA2 = A + (size_t)(n0 + ((t + 256) >> 2)) * K + ((t & 3) * 8);
    const bf16* gB1 = W16 + (size_t)(m0 + (t >> 2)) * K + ((t & 3) * 8);
    const bf16* gB2 = W16 + (size_t)(m0 + ((t + 256) >> 2)) * K + ((t & 3) * 8);
    const float* wp1 = W32 + (size_t)(m0 + (t >> 2)) * K + ((t & 3) * 8);
    const float* wp2 = W32 + (size_t)(m0 + ((t + 256) >> 2)) * K + ((t & 3) * 8);

    f32x4 acc[MF][NF] = {};

    for (int k0 = 0; k0 < K; k0 += 32) {
        __syncthreads();
        GLOAD16(gA1 + k0, As + t * 8);
        if constexpr (BM == 128) GLOAD16(gA2 + k0, As + (t + 256) * 8);
        if constexpr (WF32) {
            float4 a0 = *(const float4*)(wp1 + k0);
            float4 a1 = *(const float4*)(wp1 + k0 + 4);
            bf16x8 o;
            o[0] = (short)f2b(a0.x); o[1] = (short)f2b(a0.y);
            o[2] = (short)f2b(a0.z); o[3] = (short)f2b(a0.w);
            o[4] = (short)f2b(a1.x); o[5] = (short)f2b(a1.y);
            o[6] = (short)f2b(a1.z); o[7] = (short)f2b(a1.w);
            *(bf16x8*)(Bs + t * 8) = o;
            if constexpr (BN == 128) {
                float4 b0 = *(const float4*)(wp2 + k0);
                float4 b1 = *(const float4*)(wp2 + k0 + 4);
                bf16x8 o2;
                o2[0] = (short)f2b(b0.x); o2[1] = (short)f2b(b0.y);
                o2[2] = (short)f2b(b0.z); o2[3] = (short)f2b(b0.w);
                o2[4] = (short)f2b(b1.x); o2[5] = (short)f2b(b1.y);
                o2[6] = (short)f2b(b1.z); o2[7] = (short)f2b(b1.w);
                *(bf16x8*)(Bs + (t + 256) * 8) = o2;
            }
        } else {
            GLOAD16(gB1 + k0, Bs + t * 8);
            if constexpr (BN == 128) GLOAD16(gB2 + k0, Bs + (t + 256) * 8);
        }
        __syncthreads();

        bf16x8 af[MF], bfr[NF];
#pragma unroll
        for (int m = 0; m < MF; m++)
            af[m] = *(const bf16x8*)(As + (wr + m * 16 + qi) * 32 + g4 * 8);
#pragma unroll
        for (int n = 0; n < NF; n++)
            bfr[n] = *(const bf16x8*)(Bs + (wc + n * 16 + qi) * 32 + g4 * 8);
#pragma unroll
        for (int m = 0; m < MF; m++)
#pragma unroll
            for (int n = 0; n < NF; n++)
                acc[m][n] = __builtin_amdgcn_mfma_f32_16x16x32_bf16(af[m], bfr[n], acc[m][n], 0, 0, 0);
    }

    int colb = m0 + wc + qi;
    int rowb = n0 + wr + g4 * 4;

    if constexpr (MODE == 0 || MODE == 1) {
        float* Cf = (float*)Cv;
#pragma unroll
        for (int m = 0; m < MF; m++) {
#pragma unroll
            for (int n = 0; n < NF; n++) {
#pragma unroll
                for (int r = 0; r < 4; r++) {
                    size_t off = (size_t)(rowb + m * 16 + r) * M + (colb + n * 16);
                    float v = acc[m][n][r];
                    if (MODE == 0) __builtin_nontemporal_store(v, Cf + off);
                    else Cf[off] = v + res[off];
                }
            }
        }
    } else if constexpr (MODE == 3) {
        // interleaved g/u: even virtual col = g, odd = u; out col = vcol/2
        bf16* Cb = (bf16*)Cv;
        int M2 = M >> 1;
        bool even = (lane & 1) == 0;
#pragma unroll
        for (int m = 0; m < MF; m++) {
#pragma unroll
            for (int n = 0; n < NF; n++) {
#pragma unroll
                for (int r = 0; r < 4; r++) {
                    float own = acc[m][n][r];
                    float oth = __shfl_xor(own, 1);
                    if (even) {
                        float gg = own;
                        float sv = gg / (1.0f + __expf(-gg)) * oth;
                        int oc = (colb + n * 16) >> 1;
                        Cb[(size_t)(rowb + m * 16 + r) * M2 + oc] = __float2bfloat16(sv);
                    }
                }
            }
        }
    } else if constexpr (MODE == 4) {
        // rope/pack epilogue: tile covers heads 2*mt + (wave&1); cols d = qi + n*16
        int h = (m0 + wc) >> 6;
#pragma unroll
        for (int m = 0; m < MF; m++) {
#pragma unroll
            for (int r = 0; r < 4; r++) {
                int row = rowb + m * 16 + r;
                int tt = row & (TT - 1);
                int b = row >> 10;
                if (h < 20) {
#pragma unroll
                    for (int n = 0; n < 2; n++) {
                        int dlo = qi + n * 16;
                        float alo = acc[m][n][r];
                        float ahi = acc[m][n + 2][r];
                        float c = ct[tt * 64 + dlo];
                        float s = st[tt * 64 + dlo];
                        float olo = alo * c - ahi * s;
                        float ohi = ahi * c + alo * s;
                        if (h < 16) {
                            olo *= 0.125f; ohi *= 0.125f;
                            bf16* q = qp + (((size_t)(b * NH + h) * TT + tt) * 64);
                            q[dlo] = __float2bfloat16(olo);
                            q[dlo + 32] = __float2bfloat16(ohi);
                        } else {
                            bf16* kk = kp + (((size_t)(b * KVHN + (h - 16)) * TT + tt) * 64);
                            kk[dlo] = __float2bfloat16(olo);
                            kk[dlo + 32] = __float2bfloat16(ohi);
                        }
                    }
                } else {
                    bf16* vv = vb + (((size_t)(b * KVHN + (h - 20)) * TT + tt) * 64);
#pragma unroll
                    for (int n = 0; n < 4; n++)
                        vv[qi + n * 16] = __float2bfloat16(acc[m][n][r]);
                }
            }
        }
    }
}

extern "C" void kernel_launch(void* const* d_in, const int* in_sizes, int n_in,
                              void* d_out, int out_size, void* d_ws, size_t ws_size,
                              hipStream_t stream) {
    const int* idx    = (const int*)d_in[0];
    const float* wte  = (const float*)d_in[1];
    const float* Wq   = (const float*)d_in[2];
    const float* Wkv  = (const float*)d_in[3];
    const float* Wo   = (const float*)d_in[4];
    const float* Wg   = (const float*)d_in[5];
    const float* Wu   = (const float*)d_in[6];
    const float* Wd   = (const float*)d_in[7];
    const float* rms1 = (const float*)d_in[8];
    const float* rms2 = (const float*)d_in[9];
    const float* rmsf = (const float*)d_in[10];
    float* out = (float*)d_out;

    char* ws = (char*)d_ws;
    size_t off = 0;
    float* x = (float*)(ws + off);   off += (size_t)NTOK * DD * 4;
    bf16* xn = (bf16*)(ws + off);    off += (size_t)NTOK * DD * 2;
    float* st = (float*)(ws + off);  off += (size_t)TT * 64 * 4;
    float* ct = (float*)(ws + off);  off += (size_t)TT * 64 * 4;
    bf16* yb = (bf16*)(ws + off);    off += (size_t)NTOK * DD * 2;
    bf16* gb = (bf16*)(ws + off);    off += (size_t)NTOK * IIP * 2;
    bf16* qp = (bf16*)(ws + off);    off += (size_t)NTOK * DD * 2;
    bf16* kp = (bf16*)(ws + off);    off += (size_t)BB * KVHN * TT * 64 * 2;
    bf16* vb = (bf16*)(ws + off);    off += (size_t)BB * KVHN * TT * 64 * 2;
    bf16* vt = (bf16*)(ws + off);    off += (size_t)BB * KVHN * TT * 64 * 2;
    bf16* Wqkv_buf = (bf16*)(ws + off); off += (size_t)QKVD * DD * 2;
    bf16* Wo_buf = (bf16*)(ws + off);   off += (size_t)DD * DD * 2;
    bf16* Wgu_buf = (bf16*)(ws + off);  off += (size_t)2 * IIP * DD * 2;
    bf16* Wd_buf = (bf16*)(ws + off);   off += (size_t)DD * IIP * 2;

    rope_table_k<<<(TT * 64 + 255) / 256, 256, 0, stream>>>(st, ct);
    embed_k<<<NTOK, 256, 0, stream>>>(idx, wte, x);

    for (int l = 0; l < NL; ++l) {
        CvtJobs j;
        j.src[0] = Wq + (size_t)l * DD * DD;   j.dst[0] = Wqkv_buf;
        j.Msrc[0] = DD;  j.Ksrc[0] = DD;  j.Kdst[0] = DD;  j.n4[0] = DD * DD / 4;
        j.rmul[0] = 1; j.radd[0] = 0;
        j.src[1] = Wkv + (size_t)l * 512 * DD; j.dst[1] = Wqkv_buf + (size_t)DD * DD;
        j.Msrc[1] = 512; j.Ksrc[1] = DD;  j.Kdst[1] = DD;  j.n4[1] = 512 * DD / 4;
        j.rmul[1] = 1; j.radd[1] = 0;
        j.src[2] = Wo + (size_t)l * DD * DD;   j.dst[2] = Wo_buf;
        j.Msrc[2] = DD;  j.Ksrc[2] = DD;  j.Kdst[2] = DD;  j.n4[2] = DD * DD / 4;
        j.rmul[2] = 1; j.radd[2] = 0;
        j.src[3] = Wg + (size_t)l * II * DD;   j.dst[3] = Wgu_buf;   // -> rows 2i
        j.Msrc[3] = II;  j.Ksrc[3] = DD;  j.Kdst[3] = DD;  j.n4[3] = IIP * DD / 4;
        j.rmul[3] = 2; j.radd[3] = 0;
        j.src[4] = Wu + (size_t)l * II * DD;   j.dst[4] = Wgu_buf;   // -> rows 2i+1
        j.Msrc[4] = II;  j.Ksrc[4] = DD;  j.Kdst[4] = DD;  j.n4[4] = IIP * DD / 4;
        j.rmul[4] = 2; j.radd[4] = 1;
        j.src[5] = Wd + (size_t)l * DD * II;   j.dst[5] = Wd_buf;
        j.Msrc[5] = DD;  j.Ksrc[5] = II;  j.Kdst[5] = IIP; j.n4[5] = DD * IIP / 4;
        j.rmul[5] = 1; j.radd[5] = 0;
        cvt_fused_k<<<dim3(512, 6), 256, 0, stream>>>(j);

        // --- attention block ---
        rmsnorm_k<<<NTOK, 256, 0, stream>>>(x, rms1 + (size_t)l * DD, xn);
        gemm_bt<4, 64, 128, 0><<<(QKVD / 128) * (NTOK / 64), 256, 0, stream>>>(
            xn, Wqkv_buf, nullptr, nullptr, nullptr, NTOK, QKVD, DD,
            st, ct, qp, kp, vb);
        pack_v_k<<<dim3(TT / 64, KVHN, BB), 256, 0, stream>>>(vb, vt);
        attn_mfma_k<<<dim3(TT / 64, NH, BB), 256, 0, stream>>>(qp, kp, vt, yb);
        gemm_bt<1, 128, 64, 0><<<(DD / 64) * (NTOK / 128), 256, 0, stream>>>(
            yb, Wo_buf, nullptr, x, x, NTOK, DD, DD,
            nullptr, nullptr, nullptr, nullptr, nullptr);
        // --- mlp block ---
        rmsnorm_k<<<NTOK, 256, 0, stream>>>(x, rms2 + (size_t)l * DD, xn);
        gemm_bt<3, 128, 128, 0><<<(2 * IIP / 128) * (NTOK / 128), 256, 0, stream>>>(
            xn, Wgu_buf, nullptr, nullptr, gb, NTOK, 2 * IIP, DD,
            nullptr, nullptr, nullptr, nullptr, nullptr);
        gemm_bt<1, 128, 64, 0><<<(DD / 64) * (NTOK / 128), 256, 0, stream>>>(
            gb, Wd_buf, nullptr, x, x, NTOK, DD, IIP,
            nullptr, nullptr, nullptr, nullptr, nullptr);
    }

    // --- final norm + tied lm_head (fp32 wte read directly, NT C stores) ---
    rmsnorm_k<<<NTOK, 256, 0, stream>>>(x, rmsf, xn);
    gemm_bt<0, 128, 128, 1><<<(32000 / 128) * (NTOK / 128), 256, 0, stream>>>(
        xn, nullptr, wte, nullptr, out, NTOK, 32000, DD,
        nullptr, nullptr, nullptr, nullptr, nullptr);
}